// Round 7
// baseline (27215.060 us; speedup 1.0000x reference)
//
#include <hip/hip_runtime.h>
#include <hip/hip_bf16.h>

// ---------------------------------------------------------------------------
// 2-layer LSTM, B=32, T=512, H=1024, fp32 in/out.
// Round 7: per-XCD L2 multicast of the h-state broadcast.
//   r6 evidence: h UC-broadcast (64 MB/step, 524K L3-line reads/step, every
//   line read by all 256 wgs) runs at ~2.6 TB/s effective -> L3 bank
//   serialization is the 25us/step. Fix: one elected stager wg per XCD pulls
//   h from the coherence point ONCE (16K line reads/step, 32x less) into a
//   per-XCD staging buffer (normal write-back stores -> local L2); the other
//   wgs on that XCD read it with plain cached loads (same-XCD L2 coherent;
//   L1 thrashed 8x/step so no stale L1 hits). Barrier & stage fused:
//   arrival flags -> stagers aggregate (r6 wg0-loop) -> stage -> per-XCD
//   ready flag -> consumers poll only their ready word.
//   MFMA core / epilogue / numerics byte-identical to r6 (absmax 0.0546875).
// ---------------------------------------------------------------------------

constexpr int Hh = 1024;
constexpr int Bb = 32;
constexpr int Tt = 512;
constexpr int NWG = 256;
constexpr int PLE  = 32 * 1024;        // elems per plane [32][1024]
constexpr int ST4E = 4 * PLE;          // 4 planes per staged slot

typedef float f32x4 __attribute__((ext_vector_type(4)));
typedef int   i32x4 __attribute__((ext_vector_type(4)));

__device__ inline void mfma_bf16(f32x4& acc, i32x4 a, i32x4 b) {
    // s_nop 2 guards compiler-inserted VALU writes before the MFMA reads.
    asm("s_nop 2\n\tv_mfma_f32_16x16x32_bf16 %0, %1, %2, %0"
        : "+v"(acc) : "v"(a), "v"(b));
}

// Coherent (cross-XCD) 16B load: two relaxed agent 8B atomic loads.
__device__ inline i32x4 aload_x4(const unsigned short* p) {
    const unsigned long long* q = (const unsigned long long*)p;
    unsigned long long a = __hip_atomic_load(q,     __ATOMIC_RELAXED, __HIP_MEMORY_SCOPE_AGENT);
    unsigned long long b = __hip_atomic_load(q + 1, __ATOMIC_RELAXED, __HIP_MEMORY_SCOPE_AGENT);
    i32x4 r;
    r[0] = (int)(unsigned)a; r[1] = (int)(a >> 32);
    r[2] = (int)(unsigned)b; r[3] = (int)(b >> 32);
    return r;
}
// Plain cached 16B load (L2-local staged data).
__device__ inline i32x4 pload_x4(const unsigned short* p) {
    return *(const i32x4*)p;
}
__device__ inline void astore_u16(unsigned short* p, unsigned short v) {
    __hip_atomic_store(p, v, __ATOMIC_RELAXED, __HIP_MEMORY_SCOPE_AGENT);
}
__device__ inline void astore_u32(unsigned int* p, unsigned v) {
    __hip_atomic_store(p, v, __ATOMIC_RELAXED, __HIP_MEMORY_SCOPE_AGENT);
}
__device__ inline unsigned aload_u32(const unsigned int* p) {
    return __hip_atomic_load(p, __ATOMIC_RELAXED, __HIP_MEMORY_SCOPE_AGENT);
}

__device__ inline unsigned short f2bf(float f) {
    unsigned u = __float_as_uint(f);
    u += 0x7fffu + ((u >> 16) & 1u);   // round-to-nearest-even
    return (unsigned short)(u >> 16);
}
__device__ inline float bf2f(unsigned short s) {
    return __uint_as_float((unsigned)s << 16);
}

__device__ inline float sigm(float x)  { return 1.f / (1.f + __expf(-x)); }
__device__ inline float tanh_f(float x){ return 1.f - 2.f / (__expf(2.f * x) + 1.f); }

// x [32][512][1024] f32 -> xT hi/lo [513][32][1024] bf16 (slot 512 zeroed)
__global__ __launch_bounds__(256) void k_xT(const float* __restrict__ x,
                                            unsigned short* __restrict__ xh,
                                            unsigned short* __restrict__ xl,
                                            int use_lo) {
    int bid = blockIdx.x;               // 0..16415
    int t = bid >> 5, b = bid & 31;
    size_t o = ((size_t)t * Bb + b) * Hh;
    if (t == Tt) {
        ushort4 z = {0, 0, 0, 0};
        ((ushort4*)(xh + o))[threadIdx.x] = z;
        if (use_lo) ((ushort4*)(xl + o))[threadIdx.x] = z;
        return;
    }
    const float4* src = (const float4*)(x + ((size_t)b * Tt + t) * Hh);
    float4 v = src[threadIdx.x];
    ushort4 hi;
    hi.x = f2bf(v.x); hi.y = f2bf(v.y); hi.z = f2bf(v.z); hi.w = f2bf(v.w);
    ((ushort4*)(xh + o))[threadIdx.x] = hi;
    if (use_lo) {
        ushort4 lo;
        lo.x = f2bf(v.x - bf2f(hi.x));
        lo.y = f2bf(v.y - bf2f(hi.y));
        lo.z = f2bf(v.z - bf2f(hi.z));
        lo.w = f2bf(v.w - bf2f(hi.w));
        ((ushort4*)(xl + o))[threadIdx.x] = lo;
    }
}

// W[mat] [1024][4096] f32 -> wh[mat][wg][col(16)][k(1024)] bf16 (4 mats),
// lo planes only for mats 0,2 (w_ih0, w_ih1) packed at lo-slot mat>>1.
__global__ __launch_bounds__(256) void k_warr(const float* __restrict__ w0,
                                              const float* __restrict__ w1,
                                              const float* __restrict__ w2,
                                              const float* __restrict__ w3,
                                              unsigned short* __restrict__ wh,
                                              unsigned short* __restrict__ wl,
                                              int use_lo) {
    int bid = blockIdx.x;               // 0..1023
    int mat = bid >> 8, wg = bid & 255;
    const float* W = (mat == 0) ? w0 : (mat == 1) ? w1 : (mat == 2) ? w2 : w3;
    size_t dbase = ((size_t)(mat * NWG + wg) * 16) * Hh;
    size_t dlo   = ((size_t)(((mat >> 1) & 1) * NWG + wg) * 16) * Hh;
    const bool want_lo = use_lo && ((mat & 1) == 0);
    for (int it = 0; it < 64; ++it) {
        int idx = it * 256 + (int)threadIdx.x;
        int col = idx >> 10, k = idx & 1023;
        int cg = (col >> 2) * Hh + wg * 4 + (col & 3);
        float w = W[(size_t)k * 4096 + cg];
        unsigned short hi = f2bf(w);
        wh[dbase + (size_t)col * Hh + k] = hi;
        if (want_lo) wl[dlo + (size_t)col * Hh + k] = f2bf(w - bf2f(hi));
    }
}

template <bool USE_LO>
__global__ __launch_bounds__(256, 1) void k_lstm(
    const unsigned short* __restrict__ xTh,
    const unsigned short* __restrict__ xTl,
    const unsigned short* __restrict__ warrh,
    const unsigned short* __restrict__ warrl,
    unsigned short* __restrict__ h0h, unsigned short* __restrict__ h0l,
    unsigned short* __restrict__ h1h, unsigned short* __restrict__ h1l,
    unsigned int*   __restrict__ flags,    // [256] lines of 32 u32 (arrivals)
    unsigned int*   __restrict__ ready,    // [8] lines of 32 u32 (per-XCD go)
    int*            __restrict__ ctr,      // [8] election counters
    unsigned short* __restrict__ hstage,   // [2][8][4][32][1024] bf16
    const float* __restrict__ b0,
    const float* __restrict__ b1,
    float* __restrict__ out)
{
    __shared__ float red[2][4][32][17];     // [layer][wave][batch(row)][col(+pad)]
    __shared__ int sRank;

    const int tid  = threadIdx.x;
    const int wave = tid >> 6;
    const int l    = tid & 63;
    const int wg   = blockIdx.x;

    // ---- XCD identification + stager election (one stager per XCD) ----
    unsigned xraw;
    asm volatile("s_getreg_b32 %0, hwreg(20, 0, 32)" : "=s"(xraw));  // HW_REG_XCC_ID [m09]
    const int xcd = (int)(xraw & 7u);
    if (tid == 0) sRank = atomicAdd(&ctr[xcd], 1);
    __syncthreads();
    const bool isStager = (sRank == 0);

    // ---- persistent B fragments (weights) in registers ----
    i32x4 Bih0h[8], Bhh0h[8], Bih1h[8], Bhh1h[8];
    i32x4 Bih0l[8], Bih1l[8];
    {
        const size_t matStride = (size_t)NWG * 16 * Hh;
        const size_t wgOff = (size_t)wg * 16 * Hh;
        const int laneOff = (l & 15) * Hh + ((l >> 4) * 8);
        #pragma unroll
        for (int kk = 0; kk < 8; ++kk) {
            int off = laneOff + wave * 256 + kk * 32;
            Bih0h[kk] = *(const i32x4*)(warrh + 0 * matStride + wgOff + off);
            Bhh0h[kk] = *(const i32x4*)(warrh + 1 * matStride + wgOff + off);
            Bih1h[kk] = *(const i32x4*)(warrh + 2 * matStride + wgOff + off);
            Bhh1h[kk] = *(const i32x4*)(warrh + 3 * matStride + wgOff + off);
            if (USE_LO) {
                Bih0l[kk] = *(const i32x4*)(warrl + 0 * matStride + wgOff + off);
                Bih1l[kk] = *(const i32x4*)(warrl + 1 * matStride + wgOff + off);
            }
        }
        // Opacity: cannot be rematerialized -> stays in registers.
        #pragma unroll
        for (int kk = 0; kk < 8; ++kk) {
            asm volatile("" : "+v"(Bih0h[kk]), "+v"(Bhh0h[kk]),
                             "+v"(Bih1h[kk]), "+v"(Bhh1h[kk]));
            if (USE_LO)
                asm volatile("" : "+v"(Bih0l[kk]), "+v"(Bih1l[kk]));
        }
    }

    // ---- epilogue cell ownership: tid<128 -> layer0, tid>=128 -> layer1 ----
    const int cid = tid & 127;
    const int cb  = cid & 31;          // batch
    const int ca  = (cid >> 5) & 3;    // local unit
    const int cu  = wg * 4 + ca;       // global hidden unit
    const float* bias = (tid < 128) ? b0 : b1;
    const float bi  = bias[cu];
    const float bf_ = bias[Hh + cu];
    const float bg  = bias[2 * Hh + cu];
    const float bo  = bias[3 * Hh + cu];
    float c = 0.f;

    const int laneA = (l & 15) * Hh + ((l >> 4) * 8);

    for (int s = 0; s <= Tt; ++s) {
        const int par_w = s & 1;
        const int par_r = par_w ^ 1;
        const size_t stepOff = (size_t)s * (Bb * Hh);
        const size_t parROff = (size_t)par_r * (Bb * Hh);
        const size_t parWOff = (size_t)par_w * (Bb * Hh);
        const unsigned short* xph  = xTh + stepOff;
        const unsigned short* xpl  = xTl + stepOff;
        // staged h (this XCD's L2 copy), slot = s&1
        const unsigned short* stb  = hstage + ((size_t)(s & 1) * 8 + xcd) * ST4E;
        const unsigned short* sh0h = stb;
        const unsigned short* sh0l = stb + PLE;
        const unsigned short* sh1h = stb + 2 * PLE;
        const unsigned short* sh1l = stb + 3 * PLE;

        f32x4 a00 = {0,0,0,0}, a01 = {0,0,0,0}, a10 = {0,0,0,0}, a11 = {0,0,0,0};

        #pragma unroll
        for (int m = 0; m < 2; ++m) {
            f32x4& acc0 = m ? a01 : a00;
            f32x4& acc1 = m ? a11 : a10;

            // stage this half's h fragments from local-L2 staged copy
            i32x4 g0hv[8], g1hv[8], g0lv[8], g1lv[8];
            #pragma unroll
            for (int kk = 0; kk < 8; ++kk) {
                const int off = laneA + m * 16 * Hh + wave * 256 + kk * 32;
                g0hv[kk] = pload_x4(sh0h + off);
                g1hv[kk] = pload_x4(sh1h + off);
                if (USE_LO) {
                    g0lv[kk] = pload_x4(sh0l + off);
                    g1lv[kk] = pload_x4(sh1l + off);
                }
            }

            #pragma unroll
            for (int kk = 0; kk < 8; ++kk) {
                const int off = laneA + m * 16 * Hh + wave * 256 + kk * 32;
                i32x4 axh = *(const i32x4*)(xph + off);      // cached loads
                mfma_bf16(acc0, axh,      Bih0h[kk]);
                mfma_bf16(acc0, g0hv[kk], Bhh0h[kk]);
                mfma_bf16(acc1, g0hv[kk], Bih1h[kk]);
                mfma_bf16(acc1, g1hv[kk], Bhh1h[kk]);
                if (USE_LO) {
                    i32x4 axl = *(const i32x4*)(xpl + off);
                    mfma_bf16(acc0, axh,      Bih0l[kk]);   // x * dWih0
                    mfma_bf16(acc0, axl,      Bih0h[kk]);   // dx * Wih0
                    mfma_bf16(acc0, g0lv[kk], Bhh0h[kk]);   // dh0 * Whh0
                    mfma_bf16(acc1, g0hv[kk], Bih1l[kk]);   // y0 * dWih1
                    mfma_bf16(acc1, g0lv[kk], Bih1h[kk]);   // dy0 * Wih1
                    mfma_bf16(acc1, g1lv[kk], Bhh1h[kk]);   // dh1 * Whh1
                }
            }
        }
        asm("s_nop 7\n\ts_nop 7" : "+v"(a00), "+v"(a01), "+v"(a10), "+v"(a11)); // MFMA->VALU hazard

        {
            const int r0 = (l >> 4) * 4;   // C/D: col=lane&15, row=(lane>>4)*4+reg [m89]
            const int cc = l & 15;
            #pragma unroll
            for (int r = 0; r < 4; ++r) {
                red[0][wave][r0 + r][cc]      = a00[r];
                red[0][wave][16 + r0 + r][cc] = a01[r];
                red[1][wave][r0 + r][cc]      = a10[r];
                red[1][wave][16 + r0 + r][cc] = a11[r];
            }
        }
        __syncthreads();

        if (tid < 128) {                    // ---- layer 0 epilogue, t = s ----
            if (s < Tt) {
                float vi = bi, vf = bf_, vg = bg, vo = bo;
                #pragma unroll
                for (int w = 0; w < 4; ++w) {
                    vi += red[0][w][cb][ca];
                    vf += red[0][w][cb][4 + ca];
                    vg += red[0][w][cb][8 + ca];
                    vo += red[0][w][cb][12 + ca];
                }
                float ig = sigm(vi), fg = sigm(vf), gg = tanh_f(vg), og = sigm(vo);
                c = fg * c + ig * gg;
                float h = og * tanh_f(c);
                size_t idx = parWOff + (size_t)cb * Hh + cu;
                unsigned short hh = f2bf(h);
                astore_u16(h0h + idx, hh);
                if (USE_LO) astore_u16(h0l + idx, f2bf(h - bf2f(hh)));
                if (s == Tt - 1) {
                    out[16777216 + cb * Hh + cu] = h;          // h_n[0]
                    out[16777216 + 65536 + cb * Hh + cu] = c;  // c_n[0]
                }
            }
        } else {                            // ---- layer 1 epilogue, t = s-1 ----
            if (s >= 1) {
                const int t = s - 1;
                float vi = bi, vf = bf_, vg = bg, vo = bo;
                #pragma unroll
                for (int w = 0; w < 4; ++w) {
                    vi += red[1][w][cb][ca];
                    vf += red[1][w][cb][4 + ca];
                    vg += red[1][w][cb][8 + ca];
                    vo += red[1][w][cb][12 + ca];
                }
                float ig = sigm(vi), fg = sigm(vf), gg = tanh_f(vg), og = sigm(vo);
                c = fg * c + ig * gg;
                float h = og * tanh_f(c);
                size_t idx = parROff + (size_t)cb * Hh + cu;
                unsigned short hh = f2bf(h);
                astore_u16(h1h + idx, hh);
                if (USE_LO) astore_u16(h1l + idx, f2bf(h - bf2f(hh)));
                out[(size_t)cb * (Tt * Hh) + (size_t)t * Hh + cu] = h;   // y1
                if (s == Tt) {
                    out[16777216 + 32768 + cb * Hh + cu] = h;            // h_n[1]
                    out[16777216 + 65536 + 32768 + cb * Hh + cu] = c;    // c_n[1]
                }
            }
        }

        // ---- fused barrier + per-XCD stage ----
        if (s < Tt) {
            const unsigned tgt = (unsigned)(s + 1);
            asm volatile("s_waitcnt vmcnt(0)" ::: "memory");  // drain h UC-stores
            __syncthreads();
            if (tid == 0) astore_u32(flags + (size_t)wg * 32, tgt);  // arrival
            if (isStager) {
                // wait for ALL arrivals (thread tid polls wg tid's flag)
                int ok = 0;
                do {
                    unsigned f = aload_u32(flags + (size_t)tid * 32);
                    ok = __syncthreads_and((int)(f >= tgt));
                    if (!ok) __builtin_amdgcn_s_sleep(2);
                } while (!ok);
                // stage planes for step s+1 into this XCD's slot (s+1)&1:
                //   h0 written this step at par_w; h1 written at par_r.
                const int p  = tid >> 6;        // plane 0..3
                const int ln = tid & 63;
                const unsigned short* sp =
                    (p == 0) ? (h0h + parWOff) :
                    (p == 1) ? (h0l + parWOff) :
                    (p == 2) ? (h1h + parROff) : (h1l + parROff);
                sp += ln * 512;
                unsigned short* dp = hstage
                    + ((size_t)((s + 1) & 1) * 8 + xcd) * ST4E
                    + (size_t)p * PLE + (size_t)ln * 512;
                #pragma unroll 8
                for (int i = 0; i < 64; ++i) {
                    i32x4 v = aload_x4(sp + i * 8);          // from coherence point
                    *((i32x4*)dp + i) = v;                   // into local L2
                }
                asm volatile("s_waitcnt vmcnt(0)" ::: "memory"); // stores L2-ack'd
                __syncthreads();
                if (tid == 0) astore_u32(ready + (size_t)xcd * 32, tgt);
            } else {
                if (tid == 0) {
                    while (aload_u32(ready + (size_t)xcd * 32) < tgt)
                        __builtin_amdgcn_s_sleep(4);
                }
                __syncthreads();   // also orders the staged plain loads after poll
            }
        }
    }
}

extern "C" void kernel_launch(void* const* d_in, const int* in_sizes, int n_in,
                              void* d_out, int out_size, void* d_ws, size_t ws_size,
                              hipStream_t stream) {
    const float* x     = (const float*)d_in[0];
    const float* w_ih0 = (const float*)d_in[1];
    const float* w_hh0 = (const float*)d_in[2];
    const float* b0    = (const float*)d_in[3];
    const float* w_ih1 = (const float*)d_in[4];
    const float* w_hh1 = (const float*)d_in[5];
    const float* b1    = (const float*)d_in[6];
    float* out = (float*)d_out;

    const size_t SZ_WARRH = 33554432;   // 4*256*16*1024*2
    const size_t SZ_WARRL = 16777216;   // 2*256*16*1024*2
    const size_t SZ_XT    = 33619968;   // 513*32*1024*2
    const size_t SZ_H     = 131072;     // per plane-buffer [2][32][1024]*2B
    const size_t SZ_FLAGS = 32768;      // 256 lines x 128B
    const size_t SZ_READY = 1024;       // 8 lines x 128B
    const size_t SZ_CTR   = 256;
    const size_t SZ_STAGE = 4194304;    // 2*8*4*32*1024*2B

    char* ws = (char*)d_ws;
    unsigned short* warrh = (unsigned short*)ws;
    unsigned short* warrl = (unsigned short*)(ws + SZ_WARRH);
    unsigned short* xTh   = (unsigned short*)(ws + SZ_WARRH + SZ_WARRL);
    unsigned short* xTl   = (unsigned short*)(ws + SZ_WARRH + SZ_WARRL + SZ_XT);
    char* zbase = ws + SZ_WARRH + SZ_WARRL + 2 * SZ_XT;
    unsigned short* h0h = (unsigned short*)zbase;
    unsigned short* h0l = (unsigned short*)(zbase + SZ_H);
    unsigned short* h1h = (unsigned short*)(zbase + 2 * SZ_H);
    unsigned short* h1l = (unsigned short*)(zbase + 3 * SZ_H);
    unsigned int*   flags = (unsigned int*)(zbase + 4 * SZ_H);
    unsigned int*   ready = (unsigned int*)(zbase + 4 * SZ_H + SZ_FLAGS);
    int*            ctr   = (int*)(zbase + 4 * SZ_H + SZ_FLAGS + SZ_READY);
    unsigned short* hstage= (unsigned short*)(zbase + 4 * SZ_H + SZ_FLAGS + SZ_READY + SZ_CTR);

    const size_t ZSZ  = 4 * SZ_H + SZ_FLAGS + SZ_READY + SZ_CTR + SZ_STAGE;
    const size_t FULL = SZ_WARRH + SZ_WARRL + 2 * SZ_XT + ZSZ;
    const bool use_lo = ws_size >= FULL;

    hipMemsetAsync(zbase, 0, ZSZ, stream);   // h planes+flags+ready+ctr+stage, every launch (replay-safe)
    hipLaunchKernelGGL(k_xT,   dim3(16416), dim3(256), 0, stream, x, xTh, xTl, (int)use_lo);
    hipLaunchKernelGGL(k_warr, dim3(1024),  dim3(256), 0, stream,
                       w_ih0, w_hh0, w_ih1, w_hh1, warrh, warrl, (int)use_lo);
    if (use_lo) {
        hipLaunchKernelGGL(k_lstm<true>, dim3(256), dim3(256), 0, stream,
                           xTh, xTl, warrh, warrl, h0h, h0l, h1h, h1l,
                           flags, ready, ctr, hstage, b0, b1, out);
    } else {
        hipLaunchKernelGGL(k_lstm<false>, dim3(256), dim3(256), 0, stream,
                           xTh, xTl, warrh, warrl, h0h, h0l, h1h, h1l,
                           flags, ready, ctr, hstage, b0, b1, out);
    }
}

// Round 8
// 10364.667 us; speedup vs baseline: 2.6258x; 2.6258x over previous
//
#include <hip/hip_runtime.h>
#include <hip/hip_bf16.h>

// ---------------------------------------------------------------------------
// 2-layer LSTM, B=32, T=512, H=1024, fp32 in/out.
// Round 8: per-XCD L2 multicast, UNIFORM implementation (no divergent stager
//   branch -> no register spill; r7's VGPR 256->144 collapse was the 2x
//   regression, not the multicast concept).
//   Every wg: rank r within its XCD (atomicAdd election, r7-proven) stages
//   slice(s) r, r+nx, ... (8KB each: 2x16B UC loads + 2 plain stores/thread)
//   of the 256KB h-state into the XCD's staging buffer. Readers use plain
//   cached loads from local L2 (r7 proved non-stale, absmax bit-exact).
//   Step chain: h UC-stores drain -> arrival flag -> all-wg flag poll (r5
//   proven) -> stage -> drain -> per-XCD done-counter atomicAdd -> poll
//   counter >= nx*(s+1) -> next step reads local-L2 copy.
//   UC line-reads/step: 524K -> 16K (32x). MFMA core/epilogue/numerics
//   byte-identical to r6 (passed, absmax 0.0546875).
// ---------------------------------------------------------------------------

constexpr int Hh = 1024;
constexpr int Bb = 32;
constexpr int Tt = 512;
constexpr int NWG = 256;
constexpr int PLE  = 32 * 1024;        // elems per plane [32][1024]
constexpr int ST4E = 4 * PLE;          // 4 planes per staged slot

typedef float f32x4 __attribute__((ext_vector_type(4)));
typedef int   i32x4 __attribute__((ext_vector_type(4)));

__device__ inline void mfma_bf16(f32x4& acc, i32x4 a, i32x4 b) {
    // s_nop 2 guards compiler-inserted VALU writes before the MFMA reads.
    asm("s_nop 2\n\tv_mfma_f32_16x16x32_bf16 %0, %1, %2, %0"
        : "+v"(acc) : "v"(a), "v"(b));
}

// Coherent (cross-XCD) 16B load: two relaxed agent 8B atomic loads.
__device__ inline i32x4 aload_x4(const unsigned short* p) {
    const unsigned long long* q = (const unsigned long long*)p;
    unsigned long long a = __hip_atomic_load(q,     __ATOMIC_RELAXED, __HIP_MEMORY_SCOPE_AGENT);
    unsigned long long b = __hip_atomic_load(q + 1, __ATOMIC_RELAXED, __HIP_MEMORY_SCOPE_AGENT);
    i32x4 r;
    r[0] = (int)(unsigned)a; r[1] = (int)(a >> 32);
    r[2] = (int)(unsigned)b; r[3] = (int)(b >> 32);
    return r;
}
// Plain cached 16B load (L2-local staged data).
__device__ inline i32x4 pload_x4(const unsigned short* p) {
    return *(const i32x4*)p;
}
__device__ inline void astore_u16(unsigned short* p, unsigned short v) {
    __hip_atomic_store(p, v, __ATOMIC_RELAXED, __HIP_MEMORY_SCOPE_AGENT);
}
__device__ inline void astore_u32(unsigned int* p, unsigned v) {
    __hip_atomic_store(p, v, __ATOMIC_RELAXED, __HIP_MEMORY_SCOPE_AGENT);
}
__device__ inline unsigned aload_u32(const unsigned int* p) {
    return __hip_atomic_load(p, __ATOMIC_RELAXED, __HIP_MEMORY_SCOPE_AGENT);
}

__device__ inline unsigned short f2bf(float f) {
    unsigned u = __float_as_uint(f);
    u += 0x7fffu + ((u >> 16) & 1u);   // round-to-nearest-even
    return (unsigned short)(u >> 16);
}
__device__ inline float bf2f(unsigned short s) {
    return __uint_as_float((unsigned)s << 16);
}

__device__ inline float sigm(float x)  { return 1.f / (1.f + __expf(-x)); }
__device__ inline float tanh_f(float x){ return 1.f - 2.f / (__expf(2.f * x) + 1.f); }

// x [32][512][1024] f32 -> xT hi/lo [513][32][1024] bf16 (slot 512 zeroed)
__global__ __launch_bounds__(256) void k_xT(const float* __restrict__ x,
                                            unsigned short* __restrict__ xh,
                                            unsigned short* __restrict__ xl,
                                            int use_lo) {
    int bid = blockIdx.x;               // 0..16415
    int t = bid >> 5, b = bid & 31;
    size_t o = ((size_t)t * Bb + b) * Hh;
    if (t == Tt) {
        ushort4 z = {0, 0, 0, 0};
        ((ushort4*)(xh + o))[threadIdx.x] = z;
        if (use_lo) ((ushort4*)(xl + o))[threadIdx.x] = z;
        return;
    }
    const float4* src = (const float4*)(x + ((size_t)b * Tt + t) * Hh);
    float4 v = src[threadIdx.x];
    ushort4 hi;
    hi.x = f2bf(v.x); hi.y = f2bf(v.y); hi.z = f2bf(v.z); hi.w = f2bf(v.w);
    ((ushort4*)(xh + o))[threadIdx.x] = hi;
    if (use_lo) {
        ushort4 lo;
        lo.x = f2bf(v.x - bf2f(hi.x));
        lo.y = f2bf(v.y - bf2f(hi.y));
        lo.z = f2bf(v.z - bf2f(hi.z));
        lo.w = f2bf(v.w - bf2f(hi.w));
        ((ushort4*)(xl + o))[threadIdx.x] = lo;
    }
}

// W[mat] [1024][4096] f32 -> wh[mat][wg][col(16)][k(1024)] bf16 (4 mats),
// lo planes only for mats 0,2 (w_ih0, w_ih1) packed at lo-slot mat>>1.
__global__ __launch_bounds__(256) void k_warr(const float* __restrict__ w0,
                                              const float* __restrict__ w1,
                                              const float* __restrict__ w2,
                                              const float* __restrict__ w3,
                                              unsigned short* __restrict__ wh,
                                              unsigned short* __restrict__ wl,
                                              int use_lo) {
    int bid = blockIdx.x;               // 0..1023
    int mat = bid >> 8, wg = bid & 255;
    const float* W = (mat == 0) ? w0 : (mat == 1) ? w1 : (mat == 2) ? w2 : w3;
    size_t dbase = ((size_t)(mat * NWG + wg) * 16) * Hh;
    size_t dlo   = ((size_t)(((mat >> 1) & 1) * NWG + wg) * 16) * Hh;
    const bool want_lo = use_lo && ((mat & 1) == 0);
    for (int it = 0; it < 64; ++it) {
        int idx = it * 256 + (int)threadIdx.x;
        int col = idx >> 10, k = idx & 1023;
        int cg = (col >> 2) * Hh + wg * 4 + (col & 3);
        float w = W[(size_t)k * 4096 + cg];
        unsigned short hi = f2bf(w);
        wh[dbase + (size_t)col * Hh + k] = hi;
        if (want_lo) wl[dlo + (size_t)col * Hh + k] = f2bf(w - bf2f(hi));
    }
}

template <bool USE_LO>
__global__ __launch_bounds__(256, 1) void k_lstm(
    const unsigned short* __restrict__ xTh,
    const unsigned short* __restrict__ xTl,
    const unsigned short* __restrict__ warrh,
    const unsigned short* __restrict__ warrl,
    unsigned short* __restrict__ h0h, unsigned short* __restrict__ h0l,
    unsigned short* __restrict__ h1h, unsigned short* __restrict__ h1l,
    unsigned int*   __restrict__ flags,    // [256] lines of 32 u32 (arrivals)
    unsigned int*   __restrict__ ectr,     // [8] election ctr lines (32 u32 ea)
    unsigned int*   __restrict__ dctr,     // [8] stage-done ctr lines
    unsigned short* __restrict__ hstage,   // [2][8][4][32][1024] bf16
    const float* __restrict__ b0,
    const float* __restrict__ b1,
    float* __restrict__ out)
{
    __shared__ float red[2][4][32][17];     // [layer][wave][batch(row)][col(+pad)]
    __shared__ int sRank;

    const int tid  = threadIdx.x;
    const int wave = tid >> 6;
    const int l    = tid & 63;
    const int wg   = blockIdx.x;

    // ---- XCD identification + rank election (uniform; all wgs stage) ----
    unsigned xraw;
    asm volatile("s_getreg_b32 %0, hwreg(20, 0, 32)" : "=s"(xraw));  // HW_REG_XCC_ID [m09]
    const int xcd = (int)(xraw & 7u);
    if (tid == 0) sRank = (int)atomicAdd(&ectr[(size_t)xcd * 32], 1u);
    __syncthreads();
    const int rank = sRank;

    // ---- persistent B fragments (weights) in registers ----
    i32x4 Bih0h[8], Bhh0h[8], Bih1h[8], Bhh1h[8];
    i32x4 Bih0l[8], Bih1l[8];
    {
        const size_t matStride = (size_t)NWG * 16 * Hh;
        const size_t wgOff = (size_t)wg * 16 * Hh;
        const int laneOff = (l & 15) * Hh + ((l >> 4) * 8);
        #pragma unroll
        for (int kk = 0; kk < 8; ++kk) {
            int off = laneOff + wave * 256 + kk * 32;
            Bih0h[kk] = *(const i32x4*)(warrh + 0 * matStride + wgOff + off);
            Bhh0h[kk] = *(const i32x4*)(warrh + 1 * matStride + wgOff + off);
            Bih1h[kk] = *(const i32x4*)(warrh + 2 * matStride + wgOff + off);
            Bhh1h[kk] = *(const i32x4*)(warrh + 3 * matStride + wgOff + off);
            if (USE_LO) {
                Bih0l[kk] = *(const i32x4*)(warrl + 0 * matStride + wgOff + off);
                Bih1l[kk] = *(const i32x4*)(warrl + 1 * matStride + wgOff + off);
            }
        }
        // Opacity: cannot be rematerialized -> stays in registers.
        #pragma unroll
        for (int kk = 0; kk < 8; ++kk) {
            asm volatile("" : "+v"(Bih0h[kk]), "+v"(Bhh0h[kk]),
                             "+v"(Bih1h[kk]), "+v"(Bhh1h[kk]));
            if (USE_LO)
                asm volatile("" : "+v"(Bih0l[kk]), "+v"(Bih1l[kk]));
        }
    }

    // ---- epilogue cell ownership: tid<128 -> layer0, tid>=128 -> layer1 ----
    const int cid = tid & 127;
    const int cb  = cid & 31;          // batch
    const int ca  = (cid >> 5) & 3;    // local unit
    const int cu  = wg * 4 + ca;       // global hidden unit
    const float* bias = (tid < 128) ? b0 : b1;
    const float bi  = bias[cu];
    const float bf_ = bias[Hh + cu];
    const float bg  = bias[2 * Hh + cu];
    const float bo  = bias[3 * Hh + cu];
    float c = 0.f;

    const int laneA = (l & 15) * Hh + ((l >> 4) * 8);

    for (int s = 0; s <= Tt; ++s) {
        const int par_w = s & 1;
        const int par_r = par_w ^ 1;
        const size_t stepOff = (size_t)s * (Bb * Hh);
        const size_t parROff = (size_t)par_r * (Bb * Hh);
        const size_t parWOff = (size_t)par_w * (Bb * Hh);
        const unsigned short* xph  = xTh + stepOff;
        const unsigned short* xpl  = xTl + stepOff;
        // staged h (this XCD's local-L2 copy), slot = s&1
        const unsigned short* stb  = hstage + ((size_t)(s & 1) * 8 + xcd) * ST4E;
        const unsigned short* sh0h = stb;
        const unsigned short* sh0l = stb + PLE;
        const unsigned short* sh1h = stb + 2 * PLE;
        const unsigned short* sh1l = stb + 3 * PLE;

        f32x4 a00 = {0,0,0,0}, a01 = {0,0,0,0}, a10 = {0,0,0,0}, a11 = {0,0,0,0};

        #pragma unroll
        for (int m = 0; m < 2; ++m) {
            f32x4& acc0 = m ? a01 : a00;
            f32x4& acc1 = m ? a11 : a10;

            // this half's h fragments from the local-L2 staged copy
            i32x4 g0hv[8], g1hv[8], g0lv[8], g1lv[8];
            #pragma unroll
            for (int kk = 0; kk < 8; ++kk) {
                const int off = laneA + m * 16 * Hh + wave * 256 + kk * 32;
                g0hv[kk] = pload_x4(sh0h + off);
                g1hv[kk] = pload_x4(sh1h + off);
                if (USE_LO) {
                    g0lv[kk] = pload_x4(sh0l + off);
                    g1lv[kk] = pload_x4(sh1l + off);
                }
            }

            #pragma unroll
            for (int kk = 0; kk < 8; ++kk) {
                const int off = laneA + m * 16 * Hh + wave * 256 + kk * 32;
                i32x4 axh = *(const i32x4*)(xph + off);      // cached loads
                mfma_bf16(acc0, axh,      Bih0h[kk]);
                mfma_bf16(acc0, g0hv[kk], Bhh0h[kk]);
                mfma_bf16(acc1, g0hv[kk], Bih1h[kk]);
                mfma_bf16(acc1, g1hv[kk], Bhh1h[kk]);
                if (USE_LO) {
                    i32x4 axl = *(const i32x4*)(xpl + off);
                    mfma_bf16(acc0, axh,      Bih0l[kk]);   // x * dWih0
                    mfma_bf16(acc0, axl,      Bih0h[kk]);   // dx * Wih0
                    mfma_bf16(acc0, g0lv[kk], Bhh0h[kk]);   // dh0 * Whh0
                    mfma_bf16(acc1, g0hv[kk], Bih1l[kk]);   // y0 * dWih1
                    mfma_bf16(acc1, g0lv[kk], Bih1h[kk]);   // dy0 * Wih1
                    mfma_bf16(acc1, g1lv[kk], Bhh1h[kk]);   // dh1 * Whh1
                }
            }
        }
        asm("s_nop 7\n\ts_nop 7" : "+v"(a00), "+v"(a01), "+v"(a10), "+v"(a11)); // MFMA->VALU hazard

        {
            const int r0 = (l >> 4) * 4;   // C/D: col=lane&15, row=(lane>>4)*4+reg [m89]
            const int cc = l & 15;
            #pragma unroll
            for (int r = 0; r < 4; ++r) {
                red[0][wave][r0 + r][cc]      = a00[r];
                red[0][wave][16 + r0 + r][cc] = a01[r];
                red[1][wave][r0 + r][cc]      = a10[r];
                red[1][wave][16 + r0 + r][cc] = a11[r];
            }
        }
        __syncthreads();

        if (tid < 128) {                    // ---- layer 0 epilogue, t = s ----
            if (s < Tt) {
                float vi = bi, vf = bf_, vg = bg, vo = bo;
                #pragma unroll
                for (int w = 0; w < 4; ++w) {
                    vi += red[0][w][cb][ca];
                    vf += red[0][w][cb][4 + ca];
                    vg += red[0][w][cb][8 + ca];
                    vo += red[0][w][cb][12 + ca];
                }
                float ig = sigm(vi), fg = sigm(vf), gg = tanh_f(vg), og = sigm(vo);
                c = fg * c + ig * gg;
                float h = og * tanh_f(c);
                size_t idx = parWOff + (size_t)cb * Hh + cu;
                unsigned short hh = f2bf(h);
                astore_u16(h0h + idx, hh);
                if (USE_LO) astore_u16(h0l + idx, f2bf(h - bf2f(hh)));
                if (s == Tt - 1) {
                    out[16777216 + cb * Hh + cu] = h;          // h_n[0]
                    out[16777216 + 65536 + cb * Hh + cu] = c;  // c_n[0]
                }
            }
        } else {                            // ---- layer 1 epilogue, t = s-1 ----
            if (s >= 1) {
                const int t = s - 1;
                float vi = bi, vf = bf_, vg = bg, vo = bo;
                #pragma unroll
                for (int w = 0; w < 4; ++w) {
                    vi += red[1][w][cb][ca];
                    vf += red[1][w][cb][4 + ca];
                    vg += red[1][w][cb][8 + ca];
                    vo += red[1][w][cb][12 + ca];
                }
                float ig = sigm(vi), fg = sigm(vf), gg = tanh_f(vg), og = sigm(vo);
                c = fg * c + ig * gg;
                float h = og * tanh_f(c);
                size_t idx = parROff + (size_t)cb * Hh + cu;
                unsigned short hh = f2bf(h);
                astore_u16(h1h + idx, hh);
                if (USE_LO) astore_u16(h1l + idx, f2bf(h - bf2f(hh)));
                out[(size_t)cb * (Tt * Hh) + (size_t)t * Hh + cu] = h;   // y1
                if (s == Tt) {
                    out[16777216 + 32768 + cb * Hh + cu] = h;            // h_n[1]
                    out[16777216 + 65536 + 32768 + cb * Hh + cu] = c;    // c_n[1]
                }
            }
        }

        // ---- barrier + uniform slice staging into per-XCD L2 copy ----
        if (s < Tt) {
            const unsigned tgt = (unsigned)(s + 1);
            asm volatile("s_waitcnt vmcnt(0)" ::: "memory");  // drain h UC-stores
            __syncthreads();
            if (tid == 0) astore_u32(flags + (size_t)wg * 32, tgt);  // arrival
            // global arrival detect (r5-proven all-wg poll, tid polls wg tid)
            int ok = 0;
            do {
                unsigned f = aload_u32(flags + (size_t)tid * 32);
                ok = __syncthreads_and((int)(f >= tgt));
                if (!ok) __builtin_amdgcn_s_sleep(2);
            } while (!ok);
            // stage slice(s): slice r = plane (r>>3), 8KB chunk (r&7)
            const unsigned nx = aload_u32(ectr + (size_t)xcd * 32);  // wgs on this XCD
            unsigned short* dstb = hstage + ((size_t)((s + 1) & 1) * 8 + xcd) * ST4E;
            for (int r = rank; r < 32; r += (int)nx) {
                const int p = r >> 3;
                const int eoff = (r & 7) * 4096 + tid * 16;
                const unsigned short* sp =
                    (p == 0) ? (h0h + parWOff) :
                    (p == 1) ? (h0l + parWOff) :
                    (p == 2) ? (h1h + parROff) : (h1l + parROff);
                i32x4 v0 = aload_x4(sp + eoff);        // from coherence point
                i32x4 v1 = aload_x4(sp + eoff + 8);
                *(i32x4*)(dstb + (size_t)p * PLE + eoff)     = v0;   // into local L2
                *(i32x4*)(dstb + (size_t)p * PLE + eoff + 8) = v1;
            }
            asm volatile("s_waitcnt vmcnt(0)" ::: "memory");  // staged stores in L2
            __syncthreads();
            if (tid == 0) {
                atomicAdd(&dctr[(size_t)xcd * 32], 1u);       // device-scope
                while (aload_u32(dctr + (size_t)xcd * 32) < nx * tgt)
                    __builtin_amdgcn_s_sleep(2);
            }
            __syncthreads();
        }
    }
}

extern "C" void kernel_launch(void* const* d_in, const int* in_sizes, int n_in,
                              void* d_out, int out_size, void* d_ws, size_t ws_size,
                              hipStream_t stream) {
    const float* x     = (const float*)d_in[0];
    const float* w_ih0 = (const float*)d_in[1];
    const float* w_hh0 = (const float*)d_in[2];
    const float* b0    = (const float*)d_in[3];
    const float* w_ih1 = (const float*)d_in[4];
    const float* w_hh1 = (const float*)d_in[5];
    const float* b1    = (const float*)d_in[6];
    float* out = (float*)d_out;

    const size_t SZ_WARRH = 33554432;   // 4*256*16*1024*2
    const size_t SZ_WARRL = 16777216;   // 2*256*16*1024*2
    const size_t SZ_XT    = 33619968;   // 513*32*1024*2
    const size_t SZ_H     = 131072;     // per plane-buffer [2][32][1024]*2B
    const size_t SZ_FLAGS = 32768;      // 256 lines x 128B
    const size_t SZ_ECTR  = 1024;       // 8 lines x 128B
    const size_t SZ_DCTR  = 1024;       // 8 lines x 128B
    const size_t SZ_STAGE = 4194304;    // 2*8*4*32*1024*2B

    char* ws = (char*)d_ws;
    unsigned short* warrh = (unsigned short*)ws;
    unsigned short* warrl = (unsigned short*)(ws + SZ_WARRH);
    unsigned short* xTh   = (unsigned short*)(ws + SZ_WARRH + SZ_WARRL);
    unsigned short* xTl   = (unsigned short*)(ws + SZ_WARRH + SZ_WARRL + SZ_XT);
    char* zbase = ws + SZ_WARRH + SZ_WARRL + 2 * SZ_XT;
    unsigned short* h0h = (unsigned short*)zbase;
    unsigned short* h0l = (unsigned short*)(zbase + SZ_H);
    unsigned short* h1h = (unsigned short*)(zbase + 2 * SZ_H);
    unsigned short* h1l = (unsigned short*)(zbase + 3 * SZ_H);
    unsigned int*   flags = (unsigned int*)(zbase + 4 * SZ_H);
    unsigned int*   ectr  = (unsigned int*)(zbase + 4 * SZ_H + SZ_FLAGS);
    unsigned int*   dctr  = (unsigned int*)(zbase + 4 * SZ_H + SZ_FLAGS + SZ_ECTR);
    unsigned short* hstage= (unsigned short*)(zbase + 4 * SZ_H + SZ_FLAGS + SZ_ECTR + SZ_DCTR);

    const size_t ZSZ  = 4 * SZ_H + SZ_FLAGS + SZ_ECTR + SZ_DCTR + SZ_STAGE;
    const size_t FULL = SZ_WARRH + SZ_WARRL + 2 * SZ_XT + ZSZ;
    const bool use_lo = ws_size >= FULL;

    hipMemsetAsync(zbase, 0, ZSZ, stream);   // h planes+flags+ctrs+stage, every launch (replay-safe)
    hipLaunchKernelGGL(k_xT,   dim3(16416), dim3(256), 0, stream, x, xTh, xTl, (int)use_lo);
    hipLaunchKernelGGL(k_warr, dim3(1024),  dim3(256), 0, stream,
                       w_ih0, w_hh0, w_ih1, w_hh1, warrh, warrl, (int)use_lo);
    if (use_lo) {
        hipLaunchKernelGGL(k_lstm<true>, dim3(256), dim3(256), 0, stream,
                           xTh, xTl, warrh, warrl, h0h, h0l, h1h, h1l,
                           flags, ectr, dctr, hstage, b0, b1, out);
    } else {
        hipLaunchKernelGGL(k_lstm<false>, dim3(256), dim3(256), 0, stream,
                           xTh, xTl, warrh, warrl, h0h, h0l, h1h, h1l,
                           flags, ectr, dctr, hstage, b0, b1, out);
    }
}

// Round 9
// 8225.411 us; speedup vs baseline: 3.3087x; 1.2601x over previous
//
#include <hip/hip_runtime.h>
#include <hip/hip_bf16.h>

// ---------------------------------------------------------------------------
// 2-layer LSTM, B=32, T=512, H=1024, fp32 in/out.
// Round 9: 8-wave workgroups (512 thr), K split 8 ways per wave.
//   - Per-wave weight regs 192->96, staged-frag regs 128->64: total ~210 <
//     256 arch-VGPR ceiling -> no spill (r8's VGPR=176 was weight spill).
//   - 2 waves/SIMD (vs 1) -> L2/UC latency half-hidden.
//   - Barrier overlap: layer-0 x-projection MFMAs (h-independent) execute
//     between arrival-flag store and the arrival poll.
//   - Staging slice = 8KB = exactly one aload_x4 per thread at 512 thr.
//   Multicast protocol, numerics, epilogue logic = r8 (passed, 0.0546875).
// ---------------------------------------------------------------------------

constexpr int Hh = 1024;
constexpr int Bb = 32;
constexpr int Tt = 512;
constexpr int NWG = 256;
constexpr int PLE  = 32 * 1024;        // elems per plane [32][1024]
constexpr int ST4E = 4 * PLE;          // 4 planes per staged slot

typedef float f32x4 __attribute__((ext_vector_type(4)));
typedef int   i32x4 __attribute__((ext_vector_type(4)));

__device__ inline void mfma_bf16(f32x4& acc, i32x4 a, i32x4 b) {
    // s_nop 2 guards compiler-inserted VALU writes before the MFMA reads.
    asm("s_nop 2\n\tv_mfma_f32_16x16x32_bf16 %0, %1, %2, %0"
        : "+v"(acc) : "v"(a), "v"(b));
}

// Coherent (cross-XCD) 16B load: two relaxed agent 8B atomic loads.
__device__ inline i32x4 aload_x4(const unsigned short* p) {
    const unsigned long long* q = (const unsigned long long*)p;
    unsigned long long a = __hip_atomic_load(q,     __ATOMIC_RELAXED, __HIP_MEMORY_SCOPE_AGENT);
    unsigned long long b = __hip_atomic_load(q + 1, __ATOMIC_RELAXED, __HIP_MEMORY_SCOPE_AGENT);
    i32x4 r;
    r[0] = (int)(unsigned)a; r[1] = (int)(a >> 32);
    r[2] = (int)(unsigned)b; r[3] = (int)(b >> 32);
    return r;
}
// Plain cached 16B load (local-L2 staged data / xT / weights).
__device__ inline i32x4 pload_x4(const unsigned short* p) {
    return *(const i32x4*)p;
}
__device__ inline void astore_u16(unsigned short* p, unsigned short v) {
    __hip_atomic_store(p, v, __ATOMIC_RELAXED, __HIP_MEMORY_SCOPE_AGENT);
}
__device__ inline void astore_u32(unsigned int* p, unsigned v) {
    __hip_atomic_store(p, v, __ATOMIC_RELAXED, __HIP_MEMORY_SCOPE_AGENT);
}
__device__ inline unsigned aload_u32(const unsigned int* p) {
    return __hip_atomic_load(p, __ATOMIC_RELAXED, __HIP_MEMORY_SCOPE_AGENT);
}

__device__ inline unsigned short f2bf(float f) {
    unsigned u = __float_as_uint(f);
    u += 0x7fffu + ((u >> 16) & 1u);   // round-to-nearest-even
    return (unsigned short)(u >> 16);
}
__device__ inline float bf2f(unsigned short s) {
    return __uint_as_float((unsigned)s << 16);
}

__device__ inline float sigm(float x)  { return 1.f / (1.f + __expf(-x)); }
__device__ inline float tanh_f(float x){ return 1.f - 2.f / (__expf(2.f * x) + 1.f); }

// x [32][512][1024] f32 -> xT hi/lo [513][32][1024] bf16 (slot 512 zeroed)
__global__ __launch_bounds__(256) void k_xT(const float* __restrict__ x,
                                            unsigned short* __restrict__ xh,
                                            unsigned short* __restrict__ xl,
                                            int use_lo) {
    int bid = blockIdx.x;               // 0..16415
    int t = bid >> 5, b = bid & 31;
    size_t o = ((size_t)t * Bb + b) * Hh;
    if (t == Tt) {
        ushort4 z = {0, 0, 0, 0};
        ((ushort4*)(xh + o))[threadIdx.x] = z;
        if (use_lo) ((ushort4*)(xl + o))[threadIdx.x] = z;
        return;
    }
    const float4* src = (const float4*)(x + ((size_t)b * Tt + t) * Hh);
    float4 v = src[threadIdx.x];
    ushort4 hi;
    hi.x = f2bf(v.x); hi.y = f2bf(v.y); hi.z = f2bf(v.z); hi.w = f2bf(v.w);
    ((ushort4*)(xh + o))[threadIdx.x] = hi;
    if (use_lo) {
        ushort4 lo;
        lo.x = f2bf(v.x - bf2f(hi.x));
        lo.y = f2bf(v.y - bf2f(hi.y));
        lo.z = f2bf(v.z - bf2f(hi.z));
        lo.w = f2bf(v.w - bf2f(hi.w));
        ((ushort4*)(xl + o))[threadIdx.x] = lo;
    }
}

// W[mat] [1024][4096] f32 -> wh[mat][wg][col(16)][k(1024)] bf16 (4 mats),
// lo planes only for mats 0,2 (w_ih0, w_ih1) packed at lo-slot mat>>1.
__global__ __launch_bounds__(256) void k_warr(const float* __restrict__ w0,
                                              const float* __restrict__ w1,
                                              const float* __restrict__ w2,
                                              const float* __restrict__ w3,
                                              unsigned short* __restrict__ wh,
                                              unsigned short* __restrict__ wl,
                                              int use_lo) {
    int bid = blockIdx.x;               // 0..1023
    int mat = bid >> 8, wg = bid & 255;
    const float* W = (mat == 0) ? w0 : (mat == 1) ? w1 : (mat == 2) ? w2 : w3;
    size_t dbase = ((size_t)(mat * NWG + wg) * 16) * Hh;
    size_t dlo   = ((size_t)(((mat >> 1) & 1) * NWG + wg) * 16) * Hh;
    const bool want_lo = use_lo && ((mat & 1) == 0);
    for (int it = 0; it < 64; ++it) {
        int idx = it * 256 + (int)threadIdx.x;
        int col = idx >> 10, k = idx & 1023;
        int cg = (col >> 2) * Hh + wg * 4 + (col & 3);
        float w = W[(size_t)k * 4096 + cg];
        unsigned short hi = f2bf(w);
        wh[dbase + (size_t)col * Hh + k] = hi;
        if (want_lo) wl[dlo + (size_t)col * Hh + k] = f2bf(w - bf2f(hi));
    }
}

template <bool USE_LO>
__global__ __launch_bounds__(512, 2) void k_lstm(
    const unsigned short* __restrict__ xTh,
    const unsigned short* __restrict__ xTl,
    const unsigned short* __restrict__ warrh,
    const unsigned short* __restrict__ warrl,
    unsigned short* __restrict__ h0h, unsigned short* __restrict__ h0l,
    unsigned short* __restrict__ h1h, unsigned short* __restrict__ h1l,
    unsigned int*   __restrict__ flags,    // [256] lines of 32 u32 (arrivals)
    unsigned int*   __restrict__ ectr,     // [8] election ctr lines
    unsigned int*   __restrict__ dctr,     // [8] stage-done ctr lines
    unsigned short* __restrict__ hstage,   // [2][8][4][32][1024] bf16
    const float* __restrict__ b0,
    const float* __restrict__ b1,
    float* __restrict__ out)
{
    __shared__ float red[2][8][32][17];     // [layer][wave][batch(row)][col(+pad)]
    __shared__ int sRank;

    const int tid  = threadIdx.x;
    const int wave = tid >> 6;              // 0..7
    const int l    = tid & 63;
    const int wg   = blockIdx.x;

    // ---- XCD identification + rank election ----
    unsigned xraw;
    asm volatile("s_getreg_b32 %0, hwreg(20, 0, 32)" : "=s"(xraw));  // HW_REG_XCC_ID [m09]
    const int xcd = (int)(xraw & 7u);
    if (tid == 0) sRank = (int)atomicAdd(&ectr[(size_t)xcd * 32], 1u);
    __syncthreads();
    const int rank = sRank;

    // ---- persistent B fragments: K-slice of 128 per wave -> 4 kk frags ----
    i32x4 Bih0h[4], Bhh0h[4], Bih1h[4], Bhh1h[4];
    i32x4 Bih0l[4], Bih1l[4];
    {
        const size_t matStride = (size_t)NWG * 16 * Hh;
        const size_t wgOff = (size_t)wg * 16 * Hh;
        const int laneOff = (l & 15) * Hh + ((l >> 4) * 8);
        #pragma unroll
        for (int kk = 0; kk < 4; ++kk) {
            int off = laneOff + wave * 128 + kk * 32;
            Bih0h[kk] = pload_x4(warrh + 0 * matStride + wgOff + off);
            Bhh0h[kk] = pload_x4(warrh + 1 * matStride + wgOff + off);
            Bih1h[kk] = pload_x4(warrh + 2 * matStride + wgOff + off);
            Bhh1h[kk] = pload_x4(warrh + 3 * matStride + wgOff + off);
            if (USE_LO) {
                Bih0l[kk] = pload_x4(warrl + 0 * matStride + wgOff + off);
                Bih1l[kk] = pload_x4(warrl + 1 * matStride + wgOff + off);
            }
        }
        #pragma unroll
        for (int kk = 0; kk < 4; ++kk) {     // opacity: no remat
            asm volatile("" : "+v"(Bih0h[kk]), "+v"(Bhh0h[kk]),
                             "+v"(Bih1h[kk]), "+v"(Bhh1h[kk]));
            if (USE_LO)
                asm volatile("" : "+v"(Bih0l[kk]), "+v"(Bih1l[kk]));
        }
    }

    // ---- epilogue cell ownership (tid<256): <128 layer0, else layer1 ----
    const int cid = tid & 127;
    const int cb  = cid & 31;
    const int ca  = (cid >> 5) & 3;
    const int cu  = wg * 4 + ca;
    const float* bias = (tid < 128) ? b0 : b1;
    const float bi  = bias[cu];
    const float bf_ = bias[Hh + cu];
    const float bg  = bias[2 * Hh + cu];
    const float bo  = bias[3 * Hh + cu];
    float c = 0.f;

    const int laneA = (l & 15) * Hh + ((l >> 4) * 8);

    f32x4 a00, a01, a10, a11;

    // x-projection terms (layer 0, h-independent) for step sidx into A0/A1
    auto xterms = [&](int sidx, f32x4& A0, f32x4& A1) {
        const unsigned short* xh = xTh + (size_t)sidx * (Bb * Hh);
        const unsigned short* xl = xTl + (size_t)sidx * (Bb * Hh);
        #pragma unroll
        for (int m = 0; m < 2; ++m) {
            f32x4& A = m ? A1 : A0;
            #pragma unroll
            for (int kk = 0; kk < 4; ++kk) {
                const int off = laneA + m * 16 * Hh + wave * 128 + kk * 32;
                i32x4 axh = pload_x4(xh + off);
                mfma_bf16(A, axh, Bih0h[kk]);
                if (USE_LO) {
                    i32x4 axl = pload_x4(xl + off);
                    mfma_bf16(A, axh, Bih0l[kk]);
                    mfma_bf16(A, axl, Bih0h[kk]);
                }
            }
        }
    };

    // prologue: x-terms for step 0
    a00 = f32x4{0,0,0,0}; a01 = f32x4{0,0,0,0};
    xterms(0, a00, a01);

    for (int s = 0; s <= Tt; ++s) {
        const int par_w = s & 1;
        const int par_r = par_w ^ 1;
        const size_t parROff = (size_t)par_r * (Bb * Hh);
        const size_t parWOff = (size_t)par_w * (Bb * Hh);
        // staged h (this XCD's local-L2 copy), slot = s&1
        const unsigned short* stb  = hstage + ((size_t)(s & 1) * 8 + xcd) * ST4E;

        a10 = f32x4{0,0,0,0}; a11 = f32x4{0,0,0,0};

        // ---- h-dependent MFMA terms from staged local-L2 copy ----
        #pragma unroll
        for (int m = 0; m < 2; ++m) {
            f32x4& acc0 = m ? a01 : a00;
            f32x4& acc1 = m ? a11 : a10;
            i32x4 g0h[4], g1h[4], g0l[4], g1l[4];
            #pragma unroll
            for (int kk = 0; kk < 4; ++kk) {
                const int off = laneA + m * 16 * Hh + wave * 128 + kk * 32;
                g0h[kk] = pload_x4(stb + off);                 // h0 hi
                g1h[kk] = pload_x4(stb + 2 * PLE + off);       // h1 hi
                if (USE_LO) {
                    g0l[kk] = pload_x4(stb + PLE + off);       // h0 lo
                    g1l[kk] = pload_x4(stb + 3 * PLE + off);   // h1 lo
                }
            }
            #pragma unroll
            for (int kk = 0; kk < 4; ++kk) {
                mfma_bf16(acc0, g0h[kk], Bhh0h[kk]);   // h0 * Whh0
                mfma_bf16(acc1, g0h[kk], Bih1h[kk]);   // y0 * Wih1
                mfma_bf16(acc1, g1h[kk], Bhh1h[kk]);   // h1 * Whh1
                if (USE_LO) {
                    mfma_bf16(acc0, g0l[kk], Bhh0h[kk]);   // dh0 * Whh0
                    mfma_bf16(acc1, g0h[kk], Bih1l[kk]);   // y0 * dWih1
                    mfma_bf16(acc1, g0l[kk], Bih1h[kk]);   // dy0 * Wih1
                    mfma_bf16(acc1, g1l[kk], Bhh1h[kk]);   // dh1 * Whh1
                }
            }
        }
        asm("s_nop 7\n\ts_nop 7" : "+v"(a00), "+v"(a01), "+v"(a10), "+v"(a11));

        {
            const int r0 = (l >> 4) * 4;   // C/D: col=lane&15, row=(lane>>4)*4+reg [m89]
            const int cc = l & 15;
            #pragma unroll
            for (int r = 0; r < 4; ++r) {
                red[0][wave][r0 + r][cc]      = a00[r];
                red[0][wave][16 + r0 + r][cc] = a01[r];
                red[1][wave][r0 + r][cc]      = a10[r];
                red[1][wave][16 + r0 + r][cc] = a11[r];
            }
        }
        __syncthreads();

        if (tid < 128) {                    // ---- layer 0 epilogue, t = s ----
            if (s < Tt) {
                float vi = bi, vf = bf_, vg = bg, vo = bo;
                #pragma unroll
                for (int w = 0; w < 8; ++w) {
                    vi += red[0][w][cb][ca];
                    vf += red[0][w][cb][4 + ca];
                    vg += red[0][w][cb][8 + ca];
                    vo += red[0][w][cb][12 + ca];
                }
                float ig = sigm(vi), fg = sigm(vf), gg = tanh_f(vg), og = sigm(vo);
                c = fg * c + ig * gg;
                float h = og * tanh_f(c);
                size_t idx = parWOff + (size_t)cb * Hh + cu;
                unsigned short hh = f2bf(h);
                astore_u16(h0h + idx, hh);
                if (USE_LO) astore_u16(h0l + idx, f2bf(h - bf2f(hh)));
                if (s == Tt - 1) {
                    out[16777216 + cb * Hh + cu] = h;          // h_n[0]
                    out[16777216 + 65536 + cb * Hh + cu] = c;  // c_n[0]
                }
            }
        } else if (tid < 256) {             // ---- layer 1 epilogue, t = s-1 ----
            if (s >= 1) {
                const int t = s - 1;
                float vi = bi, vf = bf_, vg = bg, vo = bo;
                #pragma unroll
                for (int w = 0; w < 8; ++w) {
                    vi += red[1][w][cb][ca];
                    vf += red[1][w][cb][4 + ca];
                    vg += red[1][w][cb][8 + ca];
                    vo += red[1][w][cb][12 + ca];
                }
                float ig = sigm(vi), fg = sigm(vf), gg = tanh_f(vg), og = sigm(vo);
                c = fg * c + ig * gg;
                float h = og * tanh_f(c);
                size_t idx = parROff + (size_t)cb * Hh + cu;
                unsigned short hh = f2bf(h);
                astore_u16(h1h + idx, hh);
                if (USE_LO) astore_u16(h1l + idx, f2bf(h - bf2f(hh)));
                out[(size_t)cb * (Tt * Hh) + (size_t)t * Hh + cu] = h;   // y1
                if (s == Tt) {
                    out[16777216 + 32768 + cb * Hh + cu] = h;            // h_n[1]
                    out[16777216 + 65536 + 32768 + cb * Hh + cu] = c;    // c_n[1]
                }
            }
        }

        // ---- barrier + overlap(x-terms s+1) + per-XCD stage ----
        if (s < Tt) {
            const unsigned tgt = (unsigned)(s + 1);
            asm volatile("s_waitcnt vmcnt(0)" ::: "memory");  // drain h UC-stores
            __syncthreads();
            if (tid == 0) astore_u32(flags + (size_t)wg * 32, tgt);  // arrival

            // overlap: next step's x-projection MFMAs (no h dependency)
            a00 = f32x4{0,0,0,0}; a01 = f32x4{0,0,0,0};
            xterms(s + 1, a00, a01);

            // global arrival detect (tid<256 poll one wg flag each)
            int ok = 0;
            do {
                unsigned f = (tid < 256) ? aload_u32(flags + (size_t)tid * 32) : tgt;
                ok = __syncthreads_and((int)(f >= tgt));
                if (!ok) __builtin_amdgcn_s_sleep(2);
            } while (!ok);

            // stage slice(s): slice r = plane (r>>3), 8KB chunk (r&7);
            // 512 threads x 16B = one aload_x4 per thread per slice.
            const unsigned nx = aload_u32(ectr + (size_t)xcd * 32);
            unsigned short* dstb = hstage + ((size_t)((s + 1) & 1) * 8 + xcd) * ST4E;
            for (int r = rank; r < 32; r += (int)nx) {
                const int p = r >> 3;
                const int eoff = (r & 7) * 4096 + tid * 8;
                const unsigned short* sp =
                    (p == 0) ? (h0h + parWOff) :
                    (p == 1) ? (h0l + parWOff) :
                    (p == 2) ? (h1h + parROff) : (h1l + parROff);
                i32x4 v0 = aload_x4(sp + eoff);                      // coherence point
                *(i32x4*)(dstb + (size_t)p * PLE + eoff) = v0;       // local L2
            }
            asm volatile("s_waitcnt vmcnt(0)" ::: "memory");  // staged stores in L2
            __syncthreads();
            if (tid == 0) {
                atomicAdd(&dctr[(size_t)xcd * 32], 1u);       // device-scope
                while (aload_u32(dctr + (size_t)xcd * 32) < nx * tgt)
                    __builtin_amdgcn_s_sleep(2);
            }
            __syncthreads();
        }
    }
}

extern "C" void kernel_launch(void* const* d_in, const int* in_sizes, int n_in,
                              void* d_out, int out_size, void* d_ws, size_t ws_size,
                              hipStream_t stream) {
    const float* x     = (const float*)d_in[0];
    const float* w_ih0 = (const float*)d_in[1];
    const float* w_hh0 = (const float*)d_in[2];
    const float* b0    = (const float*)d_in[3];
    const float* w_ih1 = (const float*)d_in[4];
    const float* w_hh1 = (const float*)d_in[5];
    const float* b1    = (const float*)d_in[6];
    float* out = (float*)d_out;

    const size_t SZ_WARRH = 33554432;   // 4*256*16*1024*2
    const size_t SZ_WARRL = 16777216;   // 2*256*16*1024*2
    const size_t SZ_XT    = 33619968;   // 513*32*1024*2
    const size_t SZ_H     = 131072;     // per plane-buffer [2][32][1024]*2B
    const size_t SZ_FLAGS = 32768;      // 256 lines x 128B
    const size_t SZ_ECTR  = 1024;
    const size_t SZ_DCTR  = 1024;
    const size_t SZ_STAGE = 4194304;    // 2*8*4*32*1024*2B

    char* ws = (char*)d_ws;
    unsigned short* warrh = (unsigned short*)ws;
    unsigned short* warrl = (unsigned short*)(ws + SZ_WARRH);
    unsigned short* xTh   = (unsigned short*)(ws + SZ_WARRH + SZ_WARRL);
    unsigned short* xTl   = (unsigned short*)(ws + SZ_WARRH + SZ_WARRL + SZ_XT);
    char* zbase = ws + SZ_WARRH + SZ_WARRL + 2 * SZ_XT;
    unsigned short* h0h = (unsigned short*)zbase;
    unsigned short* h0l = (unsigned short*)(zbase + SZ_H);
    unsigned short* h1h = (unsigned short*)(zbase + 2 * SZ_H);
    unsigned short* h1l = (unsigned short*)(zbase + 3 * SZ_H);
    unsigned int*   flags = (unsigned int*)(zbase + 4 * SZ_H);
    unsigned int*   ectr  = (unsigned int*)(zbase + 4 * SZ_H + SZ_FLAGS);
    unsigned int*   dctr  = (unsigned int*)(zbase + 4 * SZ_H + SZ_FLAGS + SZ_ECTR);
    unsigned short* hstage= (unsigned short*)(zbase + 4 * SZ_H + SZ_FLAGS + SZ_ECTR + SZ_DCTR);

    const size_t ZSZ  = 4 * SZ_H + SZ_FLAGS + SZ_ECTR + SZ_DCTR + SZ_STAGE;
    const size_t FULL = SZ_WARRH + SZ_WARRL + 2 * SZ_XT + ZSZ;
    const bool use_lo = ws_size >= FULL;

    hipMemsetAsync(zbase, 0, ZSZ, stream);   // h planes+flags+ctrs+stage (replay-safe)
    hipLaunchKernelGGL(k_xT,   dim3(16416), dim3(256), 0, stream, x, xTh, xTl, (int)use_lo);
    hipLaunchKernelGGL(k_warr, dim3(1024),  dim3(256), 0, stream,
                       w_ih0, w_hh0, w_ih1, w_hh1, warrh, warrl, (int)use_lo);
    if (use_lo) {
        hipLaunchKernelGGL(k_lstm<true>, dim3(256), dim3(512), 0, stream,
                           xTh, xTl, warrh, warrl, h0h, h0l, h1h, h1l,
                           flags, ectr, dctr, hstage, b0, b1, out);
    } else {
        hipLaunchKernelGGL(k_lstm<false>, dim3(256), dim3(512), 0, stream,
                           xTh, xTl, warrh, warrl, h0h, h0l, h1h, h1l,
                           flags, ectr, dctr, hstage, b0, b1, out);
    }
}

// Round 11
// 7867.813 us; speedup vs baseline: 3.4590x; 1.0455x over previous
//
#include <hip/hip_runtime.h>
#include <hip/hip_bf16.h>

// ---------------------------------------------------------------------------
// 2-layer LSTM, B=32, T=512, H=1024, fp32 in/out.
// Round 11 (base = r9, 8.2ms passed; r10's 3-change bundle hung and is fully
// reverted - no AGPR constraints, no raw local atomics, no sc0 polls):
//   1. Stage-done signaling: per-(xcd,rank) done-FLAG stores replace the
//      per-XCD atomicAdd counter. r9 had 32 same-line device-scope RMWs/step
//      serializing at MALL (~3-6us/step). Flags are plain sc1 stores to
//      distinct lines + sc1 poll - the exact arrival-flag pattern proven
//      since r5. Zero steady-state RMW (election atomicAdd runs once).
//   2. h state packed (hi|lo u32): epilogue 1 sc1 store (was 2); stagers
//      load half the packets, unpack into the SAME 4 staged planes ->
//      consumer path byte-identical to r9.
//   Everything else = r9: geometry 256wg x 512thr, per-XCD L2 multicast,
//   arrival flags + all-wg poll, xterms overlap, "+v" opacity pins.
// ---------------------------------------------------------------------------

constexpr int Hh = 1024;
constexpr int Bb = 32;
constexpr int Tt = 512;
constexpr int NWG = 256;
constexpr int PLE  = 32 * 1024;        // elems per staged plane [32][1024]
constexpr int ST4E = 4 * PLE;          // 4 planes per staged slot

typedef float f32x4 __attribute__((ext_vector_type(4)));
typedef int   i32x4 __attribute__((ext_vector_type(4)));

__device__ inline void mfma_bf16(f32x4& acc, i32x4 a, i32x4 b) {
    // s_nop 2 guards compiler-inserted VALU writes before the MFMA reads.
    asm("s_nop 2\n\tv_mfma_f32_16x16x32_bf16 %0, %1, %2, %0"
        : "+v"(acc) : "v"(a), "v"(b));
}

// Coherent (cross-XCD) 16B load: two relaxed agent 8B atomic loads.
__device__ inline i32x4 aload_x4(const void* p) {
    const unsigned long long* q = (const unsigned long long*)p;
    unsigned long long a = __hip_atomic_load(q,     __ATOMIC_RELAXED, __HIP_MEMORY_SCOPE_AGENT);
    unsigned long long b = __hip_atomic_load(q + 1, __ATOMIC_RELAXED, __HIP_MEMORY_SCOPE_AGENT);
    i32x4 r;
    r[0] = (int)(unsigned)a; r[1] = (int)(a >> 32);
    r[2] = (int)(unsigned)b; r[3] = (int)(b >> 32);
    return r;
}
__device__ inline i32x4 pload_x4(const unsigned short* p) {  // plain cached
    return *(const i32x4*)p;
}
__device__ inline void astore_u32(unsigned int* p, unsigned v) {
    __hip_atomic_store(p, v, __ATOMIC_RELAXED, __HIP_MEMORY_SCOPE_AGENT);
}
__device__ inline unsigned aload_u32(const unsigned int* p) {
    return __hip_atomic_load(p, __ATOMIC_RELAXED, __HIP_MEMORY_SCOPE_AGENT);
}

__device__ inline unsigned short f2bf(float f) {
    unsigned u = __float_as_uint(f);
    u += 0x7fffu + ((u >> 16) & 1u);   // round-to-nearest-even
    return (unsigned short)(u >> 16);
}
__device__ inline float bf2f(unsigned short s) {
    return __uint_as_float((unsigned)s << 16);
}

__device__ inline float sigm(float x)  { return 1.f / (1.f + __expf(-x)); }
__device__ inline float tanh_f(float x){ return 1.f - 2.f / (__expf(2.f * x) + 1.f); }

// x [32][512][1024] f32 -> xT hi/lo [513][32][1024] bf16 (slot 512 zeroed)
__global__ __launch_bounds__(256) void k_xT(const float* __restrict__ x,
                                            unsigned short* __restrict__ xh,
                                            unsigned short* __restrict__ xl,
                                            int use_lo) {
    int bid = blockIdx.x;               // 0..16415
    int t = bid >> 5, b = bid & 31;
    size_t o = ((size_t)t * Bb + b) * Hh;
    if (t == Tt) {
        ushort4 z = {0, 0, 0, 0};
        ((ushort4*)(xh + o))[threadIdx.x] = z;
        if (use_lo) ((ushort4*)(xl + o))[threadIdx.x] = z;
        return;
    }
    const float4* src = (const float4*)(x + ((size_t)b * Tt + t) * Hh);
    float4 v = src[threadIdx.x];
    ushort4 hi;
    hi.x = f2bf(v.x); hi.y = f2bf(v.y); hi.z = f2bf(v.z); hi.w = f2bf(v.w);
    ((ushort4*)(xh + o))[threadIdx.x] = hi;
    if (use_lo) {
        ushort4 lo;
        lo.x = f2bf(v.x - bf2f(hi.x));
        lo.y = f2bf(v.y - bf2f(hi.y));
        lo.z = f2bf(v.z - bf2f(hi.z));
        lo.w = f2bf(v.w - bf2f(hi.w));
        ((ushort4*)(xl + o))[threadIdx.x] = lo;
    }
}

// W[mat] [1024][4096] f32 -> wh[mat][wg][col(16)][k(1024)] bf16 (4 mats),
// lo planes only for mats 0,2 (w_ih0, w_ih1) packed at lo-slot mat>>1.
__global__ __launch_bounds__(256) void k_warr(const float* __restrict__ w0,
                                              const float* __restrict__ w1,
                                              const float* __restrict__ w2,
                                              const float* __restrict__ w3,
                                              unsigned short* __restrict__ wh,
                                              unsigned short* __restrict__ wl,
                                              int use_lo) {
    int bid = blockIdx.x;               // 0..1023
    int mat = bid >> 8, wg = bid & 255;
    const float* W = (mat == 0) ? w0 : (mat == 1) ? w1 : (mat == 2) ? w2 : w3;
    size_t dbase = ((size_t)(mat * NWG + wg) * 16) * Hh;
    size_t dlo   = ((size_t)(((mat >> 1) & 1) * NWG + wg) * 16) * Hh;
    const bool want_lo = use_lo && ((mat & 1) == 0);
    for (int it = 0; it < 64; ++it) {
        int idx = it * 256 + (int)threadIdx.x;
        int col = idx >> 10, k = idx & 1023;
        int cg = (col >> 2) * Hh + wg * 4 + (col & 3);
        float w = W[(size_t)k * 4096 + cg];
        unsigned short hi = f2bf(w);
        wh[dbase + (size_t)col * Hh + k] = hi;
        if (want_lo) wl[dlo + (size_t)col * Hh + k] = f2bf(w - bf2f(hi));
    }
}

template <bool USE_LO>
__global__ __launch_bounds__(512, 2) void k_lstm(
    const unsigned short* __restrict__ xTh,
    const unsigned short* __restrict__ xTl,
    const unsigned short* __restrict__ warrh,
    const unsigned short* __restrict__ warrl,
    unsigned int* __restrict__ hp0,        // [2][32][1024] u32 packed hi|lo<<16
    unsigned int* __restrict__ hp1,        // [2][32][1024] u32
    unsigned int* __restrict__ flags,      // [256] lines of 32 u32 (arrivals)
    unsigned int* __restrict__ ectr,       // [8] election ctr lines
    unsigned int* __restrict__ dflags,     // [8][32] lines (stage-done flags)
    unsigned short* __restrict__ hstage,   // [2][8][4][32][1024] bf16
    const float* __restrict__ b0,
    const float* __restrict__ b1,
    float* __restrict__ out)
{
    __shared__ float red[2][8][32][17];     // [layer][wave][batch(row)][col(+pad)]
    __shared__ int sRank;

    const int tid  = threadIdx.x;
    const int wave = tid >> 6;              // 0..7
    const int l    = tid & 63;
    const int wg   = blockIdx.x;

    // ---- XCD identification + rank election (one-time RMW) ----
    unsigned xraw;
    asm volatile("s_getreg_b32 %0, hwreg(20, 0, 32)" : "=s"(xraw));  // HW_REG_XCC_ID [m09]
    const int xcd = (int)(xraw & 7u);
    if (tid == 0) sRank = (int)atomicAdd(&ectr[(size_t)xcd * 32], 1u);
    __syncthreads();
    const int rank = sRank;

    // ---- persistent B fragments: K-slice of 128 per wave -> 4 kk frags ----
    i32x4 Bih0h[4], Bhh0h[4], Bih1h[4], Bhh1h[4];
    i32x4 Bih0l[4], Bih1l[4];
    {
        const size_t matStride = (size_t)NWG * 16 * Hh;
        const size_t wgOff = (size_t)wg * 16 * Hh;
        const int laneOff = (l & 15) * Hh + ((l >> 4) * 8);
        #pragma unroll
        for (int kk = 0; kk < 4; ++kk) {
            int off = laneOff + wave * 128 + kk * 32;
            Bih0h[kk] = pload_x4(warrh + 0 * matStride + wgOff + off);
            Bhh0h[kk] = pload_x4(warrh + 1 * matStride + wgOff + off);
            Bih1h[kk] = pload_x4(warrh + 2 * matStride + wgOff + off);
            Bhh1h[kk] = pload_x4(warrh + 3 * matStride + wgOff + off);
            if (USE_LO) {
                Bih0l[kk] = pload_x4(warrl + 0 * matStride + wgOff + off);
                Bih1l[kk] = pload_x4(warrl + 1 * matStride + wgOff + off);
            }
        }
        #pragma unroll
        for (int kk = 0; kk < 4; ++kk) {     // opacity: no remat
            asm volatile("" : "+v"(Bih0h[kk]), "+v"(Bhh0h[kk]),
                             "+v"(Bih1h[kk]), "+v"(Bhh1h[kk]));
            if (USE_LO)
                asm volatile("" : "+v"(Bih0l[kk]), "+v"(Bih1l[kk]));
        }
    }

    // ---- epilogue cell ownership (tid<256): <128 layer0, else layer1 ----
    const int cid = tid & 127;
    const int cb  = cid & 31;
    const int ca  = (cid >> 5) & 3;
    const int cu  = wg * 4 + ca;
    const float* bias = (tid < 128) ? b0 : b1;
    const float bi  = bias[cu];
    const float bf_ = bias[Hh + cu];
    const float bg  = bias[2 * Hh + cu];
    const float bo  = bias[3 * Hh + cu];
    float c = 0.f;

    const int laneA = (l & 15) * Hh + ((l >> 4) * 8);

    f32x4 a00, a01, a10, a11;

    // x-projection terms (layer 0, h-independent) for step sidx
    auto xterms = [&](int sidx, f32x4& A0, f32x4& A1) {
        const unsigned short* xh = xTh + (size_t)sidx * (Bb * Hh);
        const unsigned short* xl = xTl + (size_t)sidx * (Bb * Hh);
        #pragma unroll
        for (int m = 0; m < 2; ++m) {
            f32x4& A = m ? A1 : A0;
            #pragma unroll
            for (int kk = 0; kk < 4; ++kk) {
                const int off = laneA + m * 16 * Hh + wave * 128 + kk * 32;
                i32x4 axh = pload_x4(xh + off);
                mfma_bf16(A, axh, Bih0h[kk]);
                if (USE_LO) {
                    i32x4 axl = pload_x4(xl + off);
                    mfma_bf16(A, axh, Bih0l[kk]);
                    mfma_bf16(A, axl, Bih0h[kk]);
                }
            }
        }
    };

    a00 = f32x4{0,0,0,0}; a01 = f32x4{0,0,0,0};
    xterms(0, a00, a01);

    unsigned nx = 0, nx32 = 0;  // wgs on this XCD; read lazily after barrier 1

    for (int s = 0; s <= Tt; ++s) {
        const int par_w = s & 1;
        const int par_r = par_w ^ 1;
        const size_t parWOff32 = (size_t)par_w * (Bb * Hh);
        const size_t parROff32 = (size_t)par_r * (Bb * Hh);
        const unsigned short* stb = hstage + ((size_t)(s & 1) * 8 + xcd) * ST4E;

        a10 = f32x4{0,0,0,0}; a11 = f32x4{0,0,0,0};

        // ---- h-dependent MFMA terms from staged local-L2 copy ----
        #pragma unroll
        for (int m = 0; m < 2; ++m) {
            f32x4& acc0 = m ? a01 : a00;
            f32x4& acc1 = m ? a11 : a10;
            i32x4 g0h[4], g1h[4], g0l[4], g1l[4];
            #pragma unroll
            for (int kk = 0; kk < 4; ++kk) {
                const int off = laneA + m * 16 * Hh + wave * 128 + kk * 32;
                g0h[kk] = pload_x4(stb + off);                 // h0 hi
                g1h[kk] = pload_x4(stb + 2 * PLE + off);       // h1 hi
                if (USE_LO) {
                    g0l[kk] = pload_x4(stb + PLE + off);       // h0 lo
                    g1l[kk] = pload_x4(stb + 3 * PLE + off);   // h1 lo
                }
            }
            #pragma unroll
            for (int kk = 0; kk < 4; ++kk) {
                mfma_bf16(acc0, g0h[kk], Bhh0h[kk]);   // h0 * Whh0
                mfma_bf16(acc1, g0h[kk], Bih1h[kk]);   // y0 * Wih1
                mfma_bf16(acc1, g1h[kk], Bhh1h[kk]);   // h1 * Whh1
                if (USE_LO) {
                    mfma_bf16(acc0, g0l[kk], Bhh0h[kk]);   // dh0 * Whh0
                    mfma_bf16(acc1, g0h[kk], Bih1l[kk]);   // y0 * dWih1
                    mfma_bf16(acc1, g0l[kk], Bih1h[kk]);   // dy0 * Wih1
                    mfma_bf16(acc1, g1l[kk], Bhh1h[kk]);   // dh1 * Whh1
                }
            }
        }
        asm("s_nop 7\n\ts_nop 7" : "+v"(a00), "+v"(a01), "+v"(a10), "+v"(a11));

        {
            const int r0 = (l >> 4) * 4;   // C/D: col=lane&15, row=(lane>>4)*4+reg [m89]
            const int cc = l & 15;
            #pragma unroll
            for (int r = 0; r < 4; ++r) {
                red[0][wave][r0 + r][cc]      = a00[r];
                red[0][wave][16 + r0 + r][cc] = a01[r];
                red[1][wave][r0 + r][cc]      = a10[r];
                red[1][wave][16 + r0 + r][cc] = a11[r];
            }
        }
        __syncthreads();

        if (tid < 128) {                    // ---- layer 0 epilogue, t = s ----
            if (s < Tt) {
                float vi = bi, vf = bf_, vg = bg, vo = bo;
                #pragma unroll
                for (int w = 0; w < 8; ++w) {
                    vi += red[0][w][cb][ca];
                    vf += red[0][w][cb][4 + ca];
                    vg += red[0][w][cb][8 + ca];
                    vo += red[0][w][cb][12 + ca];
                }
                float ig = sigm(vi), fg = sigm(vf), gg = tanh_f(vg), og = sigm(vo);
                c = fg * c + ig * gg;
                float h = og * tanh_f(c);
                unsigned short hh = f2bf(h);
                unsigned short hl = f2bf(h - bf2f(hh));
                astore_u32(hp0 + parWOff32 + (size_t)cb * Hh + cu,
                           (unsigned)hh | ((unsigned)hl << 16));
                if (s == Tt - 1) {
                    out[16777216 + cb * Hh + cu] = h;          // h_n[0]
                    out[16777216 + 65536 + cb * Hh + cu] = c;  // c_n[0]
                }
            }
        } else if (tid < 256) {             // ---- layer 1 epilogue, t = s-1 ----
            if (s >= 1) {
                const int t = s - 1;
                float vi = bi, vf = bf_, vg = bg, vo = bo;
                #pragma unroll
                for (int w = 0; w < 8; ++w) {
                    vi += red[1][w][cb][ca];
                    vf += red[1][w][cb][4 + ca];
                    vg += red[1][w][cb][8 + ca];
                    vo += red[1][w][cb][12 + ca];
                }
                float ig = sigm(vi), fg = sigm(vf), gg = tanh_f(vg), og = sigm(vo);
                c = fg * c + ig * gg;
                float h = og * tanh_f(c);
                unsigned short hh = f2bf(h);
                unsigned short hl = f2bf(h - bf2f(hh));
                astore_u32(hp1 + parROff32 + (size_t)cb * Hh + cu,
                           (unsigned)hh | ((unsigned)hl << 16));
                out[(size_t)cb * (Tt * Hh) + (size_t)t * Hh + cu] = h;   // y1
                if (s == Tt) {
                    out[16777216 + 32768 + cb * Hh + cu] = h;            // h_n[1]
                    out[16777216 + 65536 + 32768 + cb * Hh + cu] = c;    // c_n[1]
                }
            }
        }

        // ---- barrier + overlap(x-terms s+1) + per-XCD stage ----
        if (s < Tt) {
            const unsigned tgt = (unsigned)(s + 1);
            asm volatile("s_waitcnt vmcnt(0)" ::: "memory");  // drain packed h stores
            __syncthreads();
            if (tid == 0) astore_u32(flags + (size_t)wg * 32, tgt);  // arrival

            // overlap: next step's x-projection MFMAs (no h dependency);
            // free on the critical path - flag already stored.
            a00 = f32x4{0,0,0,0}; a01 = f32x4{0,0,0,0};
            xterms(s + 1, a00, a01);

            // global arrival detect (tid<256 poll one wg flag each)
            int ok = 0;
            do {
                unsigned f = (tid < 256) ? aload_u32(flags + (size_t)tid * 32) : tgt;
                ok = __syncthreads_and((int)(f >= tgt));
                if (!ok) __builtin_amdgcn_s_sleep(2);
            } while (!ok);

            if (nx == 0) {                   // lazy: all elections done by now
                nx = aload_u32(ectr + (size_t)xcd * 32);
                nx32 = nx < 32u ? nx : 32u;
            }

            // stage slices: slice r -> packed buffer (r>>4), 8KB chunk (r&15).
            // Each thread: 1 aload_x4 (4 packed u32) -> unpack -> 2x8B writes.
            unsigned short* dstb = hstage + ((size_t)((s + 1) & 1) * 8 + xcd) * ST4E;
            for (int r = rank; r < 32; r += (int)nx) {
                const int buf = r >> 4;
                const unsigned int* sp = (buf == 0) ? (hp0 + parWOff32)
                                                    : (hp1 + parROff32);
                const int e = (r & 15) * 2048 + tid * 4;      // u32 elem index
                i32x4 v = aload_x4(sp + e);
                ushort4 hi4, lo4;
                hi4.x = (unsigned short)((unsigned)v[0] & 0xffffu);
                lo4.x = (unsigned short)((unsigned)v[0] >> 16);
                hi4.y = (unsigned short)((unsigned)v[1] & 0xffffu);
                lo4.y = (unsigned short)((unsigned)v[1] >> 16);
                hi4.z = (unsigned short)((unsigned)v[2] & 0xffffu);
                lo4.z = (unsigned short)((unsigned)v[2] >> 16);
                hi4.w = (unsigned short)((unsigned)v[3] & 0xffffu);
                lo4.w = (unsigned short)((unsigned)v[3] >> 16);
                unsigned short* dh = dstb + (buf == 0 ? 0 : 2 * PLE) + e;
                unsigned short* dl = dstb + (buf == 0 ? PLE : 3 * PLE) + e;
                *(ushort4*)dh = hi4;                           // local L2
                *(ushort4*)dl = lo4;
            }
            asm volatile("s_waitcnt vmcnt(0)" ::: "memory");  // staged stores L2-ack'd
            __syncthreads();                                  // all threads drained
            if (tid == 0 && rank < 32)                        // stage-done flag (store, no RMW)
                astore_u32(dflags + ((size_t)xcd * 32 + rank) * 32, tgt);
            // wait for this XCD's nx32 stagers
            int ok2 = 0;
            do {
                unsigned f = (tid < (int)nx32)
                    ? aload_u32(dflags + ((size_t)xcd * 32 + tid) * 32) : tgt;
                ok2 = __syncthreads_and((int)(f >= tgt));
                if (!ok2) __builtin_amdgcn_s_sleep(2);
            } while (!ok2);
        }
    }
}

extern "C" void kernel_launch(void* const* d_in, const int* in_sizes, int n_in,
                              void* d_out, int out_size, void* d_ws, size_t ws_size,
                              hipStream_t stream) {
    const float* x     = (const float*)d_in[0];
    const float* w_ih0 = (const float*)d_in[1];
    const float* w_hh0 = (const float*)d_in[2];
    const float* b0    = (const float*)d_in[3];
    const float* w_ih1 = (const float*)d_in[4];
    const float* w_hh1 = (const float*)d_in[5];
    const float* b1    = (const float*)d_in[6];
    float* out = (float*)d_out;

    const size_t SZ_WARRH = 33554432;   // 4*256*16*1024*2
    const size_t SZ_WARRL = 16777216;   // 2*256*16*1024*2
    const size_t SZ_XT    = 33619968;   // 513*32*1024*2
    const size_t SZ_HP    = 262144;     // [2][32][1024] u32 packed, per buffer
    const size_t SZ_FLAGS = 32768;      // 256 lines x 128B
    const size_t SZ_ECTR  = 1024;       // 8 lines x 128B
    const size_t SZ_DFLG  = 32768;      // 8*32 lines x 128B
    const size_t SZ_STAGE = 4194304;    // 2*8*4*32*1024*2B

    char* ws = (char*)d_ws;
    unsigned short* warrh = (unsigned short*)ws;
    unsigned short* warrl = (unsigned short*)(ws + SZ_WARRH);
    unsigned short* xTh   = (unsigned short*)(ws + SZ_WARRH + SZ_WARRL);
    unsigned short* xTl   = (unsigned short*)(ws + SZ_WARRH + SZ_WARRL + SZ_XT);
    char* zbase = ws + SZ_WARRH + SZ_WARRL + 2 * SZ_XT;
    unsigned int* hp0    = (unsigned int*)zbase;
    unsigned int* hp1    = (unsigned int*)(zbase + SZ_HP);
    unsigned int* flags  = (unsigned int*)(zbase + 2 * SZ_HP);
    unsigned int* ectr   = (unsigned int*)(zbase + 2 * SZ_HP + SZ_FLAGS);
    unsigned int* dflags = (unsigned int*)(zbase + 2 * SZ_HP + SZ_FLAGS + SZ_ECTR);
    unsigned short* hstage =
        (unsigned short*)(zbase + 2 * SZ_HP + SZ_FLAGS + SZ_ECTR + SZ_DFLG);

    const size_t ZSZ  = 2 * SZ_HP + SZ_FLAGS + SZ_ECTR + SZ_DFLG + SZ_STAGE;
    const size_t FULL = SZ_WARRH + SZ_WARRL + 2 * SZ_XT + ZSZ;
    const bool use_lo = ws_size >= FULL;

    hipMemsetAsync(zbase, 0, ZSZ, stream);   // h+flags+ectr+dflags+stage (replay-safe)
    hipLaunchKernelGGL(k_xT,   dim3(16416), dim3(256), 0, stream, x, xTh, xTl, (int)use_lo);
    hipLaunchKernelGGL(k_warr, dim3(1024),  dim3(256), 0, stream,
                       w_ih0, w_hh0, w_ih1, w_hh1, warrh, warrl, (int)use_lo);
    if (use_lo) {
        hipLaunchKernelGGL(k_lstm<true>, dim3(256), dim3(512), 0, stream,
                           xTh, xTl, warrh, warrl, hp0, hp1,
                           flags, ectr, dflags, hstage, b0, b1, out);
    } else {
        hipLaunchKernelGGL(k_lstm<false>, dim3(256), dim3(512), 0, stream,
                           xTh, xTl, warrh, warrl, hp0, hp1,
                           flags, ectr, dflags, hstage, b0, b1, out);
    }
}